// Round 2
// baseline (368.029 us; speedup 1.0000x reference)
//
#include <hip/hip_runtime.h>
#include <math.h>

// PCEN on [F=1024, T=50000] fp32 spectrogram.
// EMA with s=0.5 truncated to a geometric FIR (error <= 2^-32) -> fully
// parallel across (row, chunk). One wave64 per chunk; 256 elements/iter
// (float4 per lane), 4-step in-lane EMA + 4-step weighted shfl_up scan.
// NOTE: use exp2f/log2f (lower to v_exp_f32/v_log_f32); __exp2f/__log2f
// are NOT HIP intrinsics and collide with glibc math.h internals.

#define F_DIM 1024
#define T_DIM 50000
#define CPR   8          // chunks per row
#define CHUNK 6400       // 256-aligned; CPR*CHUNK >= T_DIM
#define EPS_C 1e-6f

__device__ __forceinline__ float shfl_up_z(float v, int d, int lane) {
    float t = __shfl_up(v, d, 64);
    return (lane >= d) ? t : 0.0f;
}

__device__ __forceinline__ float4 load_g(const float* __restrict__ xr, int base, int lane) {
    int t = base + 4 * lane;
    if (base + 256 <= T_DIM) {
        return *reinterpret_cast<const float4*>(xr + t);
    }
    float4 v;
    v.x = (t + 0 < T_DIM) ? xr[t + 0] : 0.0f;
    v.y = (t + 1 < T_DIM) ? xr[t + 1] : 0.0f;
    v.z = (t + 2 < T_DIM) ? xr[t + 2] : 0.0f;
    v.w = (t + 3 < T_DIM) ? xr[t + 3] : 0.0f;
    return v;
}

template <bool RHALF>
__device__ __forceinline__ float epi(float xj, float mj, float alpha, float rv,
                                     float delta, float dr) {
    float u = xj * exp2f(-alpha * log2f(EPS_C + mj)) + delta;
    float y = RHALF ? sqrtf(u) : exp2f(rv * log2f(u));
    return y - dr;
}

template <bool RHALF>
__device__ void pcen_chunk(const float* __restrict__ xr, float* __restrict__ yr,
                           int chunk, int lane, float alpha, float rv,
                           float delta, float dr) {
    const int cstart = chunk * CHUNK;
    const int cend   = min(cstart + CHUNK, T_DIM);
    const float w16  = ldexpf(1.0f, -4 * lane);   // 16^-lane (->0 for lane>=32, fine)
    float carry = 0.0f;

    int it   = (chunk == 0) ? 0 : -1;             // it==-1: warm-up group, no store
    int base = cstart + it * 256;
    float4 xv = load_g(xr, base, lane);           // prefetched

    for (; base < cend; ++it, base += 256) {
        float4 xc = xv;
        int nb = base + 256;
        if (nb < cend) xv = load_g(xr, nb, lane); // software-pipelined prefetch

        // in-lane EMA (zero incoming), b_j = sum_{i<=j} 0.5^{j-i+1} x_i
        float b0 = 0.5f * xc.x;
        float b1 = 0.5f * xc.y + 0.5f * b0;
        float b2 = 0.5f * xc.z + 0.5f * b1;
        float b3 = 0.5f * xc.w + 0.5f * b2;

        // weighted inclusive scan of lane summaries: S_l = sum 16^-(l-m) * b3_m
        float S = b3;
        S += 0x1.0p-4f  * shfl_up_z(S, 1, lane);
        S += 0x1.0p-8f  * shfl_up_z(S, 2, lane);
        S += 0x1.0p-16f * shfl_up_z(S, 4, lane);
        S += 0x1.0p-32f * shfl_up_z(S, 8, lane);

        // incoming state at this lane's first element:
        // X_l = S_{l-1} + 16^-l * carry   (carry = EMA value at group start - 1)
        float X = shfl_up_z(S, 1, lane) + w16 * carry;

        float m0 = b0 + 0.5f    * X;
        float m1 = b1 + 0.25f   * X;
        float m2 = b2 + 0.125f  * X;
        float m3 = b3 + 0.0625f * X;

        // next group's carry = EMA at element 255 (old carry's weight 2^-256 -> 0)
        carry = __shfl(S, 63, 64);

        if (it >= 0) {
            int t = base + 4 * lane;
            float4 o;
            o.x = epi<RHALF>(xc.x, m0, alpha, rv, delta, dr);
            o.y = epi<RHALF>(xc.y, m1, alpha, rv, delta, dr);
            o.z = epi<RHALF>(xc.z, m2, alpha, rv, delta, dr);
            o.w = epi<RHALF>(xc.w, m3, alpha, rv, delta, dr);
            if (base + 256 <= T_DIM) {
                *reinterpret_cast<float4*>(yr + t) = o;
            } else {
                if (t + 0 < T_DIM) yr[t + 0] = o.x;
                if (t + 1 < T_DIM) yr[t + 1] = o.y;
                if (t + 2 < T_DIM) yr[t + 2] = o.z;
                if (t + 3 < T_DIM) yr[t + 3] = o.w;
            }
        }
    }
}

__global__ __launch_bounds__(256, 8)
void pcen_kernel(const float* __restrict__ x, const float* __restrict__ pa,
                 const float* __restrict__ pr, const float* __restrict__ pd,
                 float* __restrict__ out) {
    const int lane  = threadIdx.x & 63;
    const int gw    = blockIdx.x * 4 + (threadIdx.x >> 6);
    const int row   = gw >> 3;          // CPR == 8
    const int chunk = gw & (CPR - 1);

    const float alpha = pa[0];
    const float rv    = pr[0];
    const float delta = pd[0];

    const float* xr = x   + (size_t)row * T_DIM;
    float*       yr = out + (size_t)row * T_DIM;

    if (rv == 0.5f) {
        pcen_chunk<true >(xr, yr, chunk, lane, alpha, rv, delta, sqrtf(delta));
    } else {
        pcen_chunk<false>(xr, yr, chunk, lane, alpha, rv, delta,
                          exp2f(rv * log2f(delta)));
    }
}

extern "C" void kernel_launch(void* const* d_in, const int* in_sizes, int n_in,
                              void* d_out, int out_size, void* d_ws, size_t ws_size,
                              hipStream_t stream) {
    const float* x  = (const float*)d_in[0];
    const float* pa = (const float*)d_in[1];
    const float* pr = (const float*)d_in[2];
    const float* pd = (const float*)d_in[3];
    float* out = (float*)d_out;

    const int blocks = F_DIM * CPR / 4;  // 4 waves per 256-thread block
    pcen_kernel<<<blocks, 256, 0, stream>>>(x, pa, pr, pd, out);
}